// Round 17
// baseline (84.707 us; speedup 1.0000x reference)
//
#include <hip/hip_runtime.h>

typedef __attribute__((ext_vector_type(8))) _Float16 f16x8;
typedef __attribute__((ext_vector_type(4))) _Float16 f16x4;
typedef __attribute__((ext_vector_type(4))) float f32x4;
typedef __attribute__((ext_vector_type(4))) unsigned short u16x4;

#define SOFF 32768
#define LDS_BYTES (32768 + 4096)   // h1/h2 f16 [64][256] aliased; 4 s4-partial strips
#define NPTS 262144
#define PGRID 1024

// h1/h2: f16 [64 rows][256 cols], row stride 512B, XOR-swizzled
__device__ inline unsigned swz_h(unsigned row, unsigned colbyte){
  return row*512u + (colbyte ^ ((row & 7u) << 4));
}

__device__ inline f16x8 cvt8(f32x4 a, f32x4 b){
  f16x8 r;
  #pragma unroll
  for (int i = 0; i < 4; ++i){ r[i] = (_Float16)a[i]; r[4+i] = (_Float16)b[i]; }
  return r;
}

__device__ inline unsigned short f16bits(float f){
  _Float16 h = (_Float16)f;
  return *(unsigned short*)&h;
}
__device__ inline _Float16 bits16(unsigned short u){
  return *(_Float16*)&u;
}

// ---- merged prep (70 blocks): 0-63 W2 tile; 64 w1h; 65-68 base1; 69 head fold ----
__global__ void prep_all(const float* __restrict__ gf, const float* __restrict__ off,
                         const float* __restrict__ W1, const float* __restrict__ b1,
                         const float* __restrict__ W2,
                         const float* __restrict__ W3, const float* __restrict__ b3,
                         const float* __restrict__ Ws, const float* __restrict__ bs,
                         const float* __restrict__ Wc, const float* __restrict__ bc,
                         _Float16* __restrict__ w2t, _Float16* __restrict__ w1h,
                         _Float16* __restrict__ base1h,
                         _Float16* __restrict__ whd, _Float16* __restrict__ wlf,
                         float* __restrict__ hcon, int* __restrict__ counter){
  const int blk = blockIdx.x, tid = threadIdx.x;
  if (blk < 64){
    #pragma unroll
    for (int k = 0; k < 4; ++k){
      int e = blk*1024 + k*256 + tid;
      int s = e >> 13, r = e & 8191, n = r >> 5, kk = r & 31;
      w2t[e] = (_Float16)W2[(s*32 + kk)*256 + n];
    }
  } else if (blk == 64){
    #pragma unroll
    for (int k = 0; k < 3; ++k){
      int e = k*256 + tid;
      int d = e >> 8, j = e & 255;
      w1h[e] = (_Float16)W1[(256 + d)*256 + j];
    }
  } else if (blk < 69){
    int b = blk - 65, j = tid;
    float acc = b1[j];
    for (int k = 0; k < 256; ++k) acc += gf[b*256 + k] * W1[k*256 + j];
    for (int d = 0; d < 3; ++d)  acc -= off[b*3 + d] * W1[(256 + d)*256 + j];
    base1h[b*256 + j] = (_Float16)acc;
  } else {
    int k = tid;      // 0..255
    float s0 = 0.f, s1 = 0.f, s2 = 0.f, s3 = 0.f;
    for (int j = 0; j < 128; ++j){
      float w3 = W3[k*128 + j];
      s0 += w3 * Ws[j];
      s1 += w3 * Wc[j*3 + 0];
      s2 += w3 * Wc[j*3 + 1];
      s3 += w3 * Wc[j*3 + 2];
    }
    int base = (k >> 5)*512 + (k & 31);
    whd[base + 0*32] = (_Float16)s0;
    whd[base + 1*32] = (_Float16)s1;
    whd[base + 2*32] = (_Float16)s2;
    whd[base + 3*32] = (_Float16)s3;
    for (int o = 4; o < 16; ++o) whd[base + o*32] = (_Float16)0.f;
    if (k < 128){
      int bl = (k >> 5)*512 + (k & 31);
      wlf[bl + 0*32] = (_Float16)Ws[k];
      wlf[bl + 1*32] = (_Float16)Wc[k*3 + 0];
      wlf[bl + 2*32] = (_Float16)Wc[k*3 + 1];
      wlf[bl + 3*32] = (_Float16)Wc[k*3 + 2];
      for (int o = 4; o < 16; ++o) wlf[bl + o*32] = (_Float16)0.f;
    }
    if (k == 0){
      float c0 = bs[0], c1 = bc[0], c2 = bc[1], c3 = bc[2];
      for (int j = 0; j < 128; ++j){
        float bj = b3[j];
        c0 += bj * Ws[j];
        c1 += bj * Wc[j*3 + 0];
        c2 += bj * Wc[j*3 + 1];
        c3 += bj * Wc[j*3 + 2];
      }
      hcon[0] = c0; hcon[1] = c1; hcon[2] = c2; hcon[3] = c3;
      *counter = 0;               // stream order: done before compact_mask runs
    }
  }
}

// ---- compaction + x-packing + zero-write for masked points ----
// px8[slot] = {f16(x0), f16(x1), f16(x2), pi_low16}; pib[slot] = pi>>16 (batch, 2 bits).
// Slot order across blocks is non-deterministic but per-point results depend only on
// that point's row, so final out content is deterministic.
__global__ void compact_mask(const int* __restrict__ mk, const float* __restrict__ x,
                             u16x4* __restrict__ px8, unsigned char* __restrict__ pib,
                             int* __restrict__ counter, float* __restrict__ out){
  __shared__ int woff[16];
  __shared__ int sbase;
  const int tid = threadIdx.x;
  const int i = blockIdx.x*1024 + tid;
  const int lane = tid & 63, w = tid >> 6;
  int m = (mk[i] != 0);
  unsigned long long bal = __ballot(m);
  if (lane == 0) woff[w] = __popcll(bal);
  __syncthreads();
  if (tid == 0){
    int tot = 0;
    #pragma unroll
    for (int k = 0; k < 16; ++k){ int c = woff[k]; woff[k] = tot; tot += c; }
    sbase = atomicAdd(counter, tot);
  }
  __syncthreads();
  if (m){
    int off = __popcll(bal & ((1ull << lane) - 1ull));
    int slot = sbase + woff[w] + off;
    u16x4 r;
    r[0] = f16bits(x[i*3 + 0]);
    r[1] = f16bits(x[i*3 + 1]);
    r[2] = f16bits(x[i*3 + 2]);
    r[3] = (unsigned short)(i & 0xFFFF);
    px8[slot] = r;
    pib[slot] = (unsigned char)(i >> 16);
  } else {
    *(f32x4*)(out + (size_t)i*4) = (f32x4)0.f;
  }
}

// ---- persistent fused main: 1024 blocks, stride loop over compacted 64-pt tiles ----
// All slot reads are unclamped: reconstructed pi = (b&3)<<16|lo is always < NPTS, so
// garbage slots (>= nv, incl. 0xAA poison) give safe addresses; garbage rows are
// row-independent through both GEMMs and never written out.
__global__ __launch_bounds__(256, 4) void field_main(
    const float* __restrict__ rdv,
    const float* __restrict__ lf, const float* __restrict__ b2v,
    const _Float16* __restrict__ base1h, const _Float16* __restrict__ w1h,
    const _Float16* __restrict__ w2t, const _Float16* __restrict__ whd,
    const _Float16* __restrict__ wlf, const float* __restrict__ hcon,
    const float* __restrict__ Wc, const u16x4* __restrict__ px8,
    const unsigned char* __restrict__ pib,
    const int* __restrict__ nvp, float* __restrict__ out)
{
  const int nv = *nvp;
  const int ntiles = (nv + 63) >> 6;
  __shared__ char lds[LDS_BYTES];
  const int tid = threadIdx.x;
  const int wid = tid >> 6, lane = tid & 63;
  const int arow = lane & 15, kgrp = lane >> 4;
  const int cw = wid * 64;              // this wave's 64-column slice

  for (int tile = blockIdx.x; tile < ntiles; tile += PGRID){
    const int t0 = tile * 64;

    // early prefetch for the epilogue (wave 0 lanes use these)
    int pi_e = 0; float r0 = 0.f, r1 = 0.f, r2 = 0.f;
    if (tid < 64){
      u16x4 px = px8[t0 + tid];
      pi_e = ((pib[t0 + tid] & 3) << 16) | px[3];
      const float* rp = rdv + (pi_e >> 5)*3;
      r0 = rp[0]; r1 = rp[1]; r2 = rp[2];
    }

    // ---- layer 1: h1 = relu(base1[b] + x @ W1x); x from packed records ----
    {
      const int j0 = (tid & 31) * 8;      // 8 cols per thread
      const int mb = (tid >> 5) * 8;      // 8 rows per thread
      f16x8 w0  = *(const f16x8*)(w1h +   0 + j0);
      f16x8 w1v = *(const f16x8*)(w1h + 256 + j0);
      f16x8 w2v = *(const f16x8*)(w1h + 512 + j0);
      const f16x8 z8 = (f16x8)(_Float16)0;
      #pragma unroll
      for (int m = 0; m < 8; ++m){
        int ii = t0 + mb + m;
        u16x4 px = px8[ii];
        int b = pib[ii] & 3;
        f16x8 bh = *(const f16x8*)(base1h + b*256 + j0);
        _Float16 X0 = bits16(px[0]);
        _Float16 X1 = bits16(px[1]);
        _Float16 X2 = bits16(px[2]);
        f16x8 t = bh;
        t += w0  * X0;
        t += w1v * X1;
        t += w2v * X2;
        t = __builtin_elementwise_max(t, z8);
        *(f16x8*)(lds + swz_h(mb + m, j0*2)) = t;
      }
    }
    __syncthreads();                      // (1) h1 complete

    // ---- layer 2: h2 = relu(h1 @ W2 + b2); wave = all 64 rows x its 64 cols ----
    f32x4 acc[16];
    #pragma unroll
    for (int c = 0; c < 4; ++c){
      f32x4 bb = *(const f32x4*)(b2v + cw + c*16 + kgrp*4);
      #pragma unroll
      for (int r = 0; r < 4; ++r) acc[r*4+c] = bb;
    }
    #pragma unroll 2
    for (int s = 0; s < 8; ++s){
      f16x8 af[4], bf[4];
      #pragma unroll
      for (int r = 0; r < 4; ++r)
        af[r] = *(const f16x8*)(lds + swz_h(r*16 + arow, s*64 + kgrp*16));
      #pragma unroll
      for (int c = 0; c < 4; ++c)
        bf[c] = *(const f16x8*)(w2t + s*8192 + (cw + c*16 + arow)*32 + kgrp*8);
      __builtin_amdgcn_s_setprio(1);
      #pragma unroll
      for (int r = 0; r < 4; ++r)
        #pragma unroll
        for (int c = 0; c < 4; ++c)
          acc[r*4+c] = __builtin_amdgcn_mfma_f32_16x16x32_f16(bf[c], af[r], acc[r*4+c], 0, 0, 0);
      __builtin_amdgcn_s_setprio(0);
    }

    // lf gathers issued NOW: HBM latency hides under writeback + head MFMAs.
    f32x4 lfa[4], lfb[4];
    #pragma unroll
    for (int c = 0; c < 4; ++c){
      int ii = t0 + c*16 + arow;
      int pic = ((pib[ii] & 3) << 16) | px8[ii][3];
      const float* lp = lf + (size_t)pic*128 + wid*32 + kgrp*8;
      lfa[c] = *(const f32x4*)lp;
      lfb[c] = *(const f32x4*)(lp + 4);
    }
    __syncthreads();                      // (2) all h1 reads done

    // h2 writeback: own cols of all 64 rows -> ds_write_b64
    #pragma unroll
    for (int r = 0; r < 4; ++r)
      #pragma unroll
      for (int c = 0; c < 4; ++c){
        int row = r*16 + arow;
        int colbyte = (cw + c*16 + kgrp*4) * 2;
        f16x4 v;
        #pragma unroll
        for (int j = 0; j < 4; ++j) v[j] = (_Float16)fmaxf(acc[r*4+c][j], 0.f);
        *(f16x4*)(lds + swz_h(row, colbyte)) = v;
      }

    // ---- self-contained head partials over this wave's K-slices ----
    f32x4 acc4h[4];
    #pragma unroll
    for (int c = 0; c < 4; ++c)
      #pragma unroll
      for (int j = 0; j < 4; ++j)
        acc4h[c][j] = (wid == 0 && kgrp == 0) ? hcon[j] : 0.f;

    // h2 part: K = own 64 cols (reads ONLY locations this wave wrote)
    #pragma unroll
    for (int s = 0; s < 2; ++s){
      f16x8 ah = *(const f16x8*)(whd + (wid*2 + s)*512 + arow*32 + kgrp*8); // A[o][k]
      #pragma unroll
      for (int c = 0; c < 4; ++c){
        f16x8 bh2 = *(const f16x8*)(lds + swz_h(c*16 + arow, (cw + s*32 + kgrp*8)*2));
        acc4h[c] = __builtin_amdgcn_mfma_f32_16x16x32_f16(ah, bh2, acc4h[c], 0, 0, 0);
      }
    }
    // lf part: K-slice [wid*32, wid*32+32)
    {
      f16x8 afl = *(const f16x8*)(wlf + wid*512 + arow*32 + kgrp*8);        // A[o][k]
      #pragma unroll
      for (int c = 0; c < 4; ++c)
        acc4h[c] = __builtin_amdgcn_mfma_f32_16x16x32_f16(afl, cvt8(lfa[c], lfb[c]), acc4h[c], 0, 0, 0);
    }
    // write this wave's partial strip
    if (kgrp == 0){
      #pragma unroll
      for (int c = 0; c < 4; ++c)
        *(f32x4*)(lds + SOFF + wid*1024 + (c*16 + arow)*16) = acc4h[c];
    }
    __syncthreads();                      // (3) all strips complete

    // ---- epilogue: 1 lane per point, sum 4 partials, scatter ----
    // (other waves may run ahead into next tile's layer-1: h1 region is disjoint
    //  from strips, and barrier (1) re-aligns before any strip overwrite)
    if (tid < 64 && t0 + tid < nv){
      f32x4 v = *(const f32x4*)(lds + SOFF + 0*1024 + tid*16);
      #pragma unroll
      for (int w = 1; w < 4; ++w)
        v += *(const f32x4*)(lds + SOFF + w*1024 + tid*16);
      float ps = v[0] - 1.0f;
      float shape = (ps > 20.f) ? ps : log1pf(expf(ps));
      float c0 = v[1] + r0*Wc[128*3+0] + r1*Wc[129*3+0] + r2*Wc[130*3+0];
      float c1 = v[2] + r0*Wc[128*3+1] + r1*Wc[129*3+1] + r2*Wc[130*3+1];
      float c2 = v[3] + r0*Wc[128*3+2] + r1*Wc[129*3+2] + r2*Wc[130*3+2];
      f32x4 o;
      o[0] = shape;
      o[1] = 1.f/(1.f + expf(-c0));
      o[2] = 1.f/(1.f + expf(-c1));
      o[3] = 1.f/(1.f + expf(-c2));
      *(f32x4*)(out + (size_t)pi_e*4) = o;
    }
  }
}

extern "C" void kernel_launch(void* const* d_in, const int* in_sizes, int n_in,
                              void* d_out, int out_size, void* d_ws, size_t ws_size,
                              hipStream_t stream){
  const float* x   = (const float*)d_in[0];
  const float* rd  = (const float*)d_in[1];
  const int*   mk  = (const int*)d_in[2];
  const float* gf  = (const float*)d_in[3];
  const float* off = (const float*)d_in[4];
  const float* lf  = (const float*)d_in[5];
  const float* W1  = (const float*)d_in[6];
  const float* b1  = (const float*)d_in[7];
  const float* W2  = (const float*)d_in[8];
  const float* b2  = (const float*)d_in[9];
  const float* W3  = (const float*)d_in[10];
  const float* b3  = (const float*)d_in[11];
  const float* Ws  = (const float*)d_in[12];
  const float* bs  = (const float*)d_in[13];
  const float* Wc  = (const float*)d_in[14];
  const float* bc  = (const float*)d_in[15];

  char* ws = (char*)d_ws;
  _Float16* base1h    = (_Float16*)(ws + 0);         // 2048 B
  _Float16* w1h       = (_Float16*)(ws + 2048);      // 1536 B
  _Float16* w2t       = (_Float16*)(ws + 4096);      // 131072 B
  _Float16* whd       = (_Float16*)(ws + 135168);    // 8192 B
  _Float16* wlf       = (_Float16*)(ws + 143360);    // 4096 B
  float*    hcon      = (float*)   (ws + 147456);    // 16 B
  int*      counter   = (int*)     (ws + 147472);    // 4 B
  u16x4*    px8       = (u16x4*)   (ws + 147712);    // 2 MB
  unsigned char* pib  = (unsigned char*)(ws + 147712 + NPTS*8);  // 256 KB

  prep_all<<<70, 256, 0, stream>>>(gf, off, W1, b1, W2, W3, b3, Ws, bs, Wc, bc,
                                   w2t, w1h, base1h, whd, wlf, hcon, counter);
  compact_mask<<<NPTS/1024, 1024, 0, stream>>>(mk, x, px8, pib, counter, (float*)d_out);
  field_main<<<PGRID, 256, 0, stream>>>(rd, lf, b2,
                                        base1h, w1h, w2t, whd, wlf, hcon, Wc,
                                        px8, pib, counter, (float*)d_out);
}

// Round 18
// 59.261 us; speedup vs baseline: 1.4294x; 1.4294x over previous
//
#include <hip/hip_runtime.h>

typedef __attribute__((ext_vector_type(8))) _Float16 f16x8;
typedef __attribute__((ext_vector_type(4))) _Float16 f16x4;
typedef __attribute__((ext_vector_type(4))) float f32x4;
typedef __attribute__((ext_vector_type(4))) unsigned short u16x4;

#define SOFF 32768
#define LDS_BYTES (32768 + 4096)   // h1/h2 f16 [64][256] aliased; 4 s4-partial strips
#define NPTS 262144

// h1/h2: f16 [64 rows][256 cols], row stride 512B, XOR-swizzled
__device__ inline unsigned swz_h(unsigned row, unsigned colbyte){
  return row*512u + (colbyte ^ ((row & 7u) << 4));
}

__device__ inline f16x8 cvt8(f32x4 a, f32x4 b){
  f16x8 r;
  #pragma unroll
  for (int i = 0; i < 4; ++i){ r[i] = (_Float16)a[i]; r[4+i] = (_Float16)b[i]; }
  return r;
}

__device__ inline unsigned short f16bits(float f){
  _Float16 h = (_Float16)f;
  return *(unsigned short*)&h;
}
__device__ inline _Float16 bits16(unsigned short u){
  return *(_Float16*)&u;
}

// ---- merged prep (70 blocks): 0-63 W2 tile; 64 w1h; 65-68 base1; 69 head fold ----
__global__ void prep_all(const float* __restrict__ gf, const float* __restrict__ off,
                         const float* __restrict__ W1, const float* __restrict__ b1,
                         const float* __restrict__ W2,
                         const float* __restrict__ W3, const float* __restrict__ b3,
                         const float* __restrict__ Ws, const float* __restrict__ bs,
                         const float* __restrict__ Wc, const float* __restrict__ bc,
                         _Float16* __restrict__ w2t, _Float16* __restrict__ w1h,
                         _Float16* __restrict__ base1h,
                         _Float16* __restrict__ whd, _Float16* __restrict__ wlf,
                         float* __restrict__ hcon, int* __restrict__ counter){
  const int blk = blockIdx.x, tid = threadIdx.x;
  if (blk < 64){
    #pragma unroll
    for (int k = 0; k < 4; ++k){
      int e = blk*1024 + k*256 + tid;
      int s = e >> 13, r = e & 8191, n = r >> 5, kk = r & 31;
      w2t[e] = (_Float16)W2[(s*32 + kk)*256 + n];
    }
  } else if (blk == 64){
    #pragma unroll
    for (int k = 0; k < 3; ++k){
      int e = k*256 + tid;
      int d = e >> 8, j = e & 255;
      w1h[e] = (_Float16)W1[(256 + d)*256 + j];
    }
  } else if (blk < 69){
    int b = blk - 65, j = tid;
    float acc = b1[j];
    for (int k = 0; k < 256; ++k) acc += gf[b*256 + k] * W1[k*256 + j];
    for (int d = 0; d < 3; ++d)  acc -= off[b*3 + d] * W1[(256 + d)*256 + j];
    base1h[b*256 + j] = (_Float16)acc;
  } else {
    int k = tid;      // 0..255
    float s0 = 0.f, s1 = 0.f, s2 = 0.f, s3 = 0.f;
    for (int j = 0; j < 128; ++j){
      float w3 = W3[k*128 + j];
      s0 += w3 * Ws[j];
      s1 += w3 * Wc[j*3 + 0];
      s2 += w3 * Wc[j*3 + 1];
      s3 += w3 * Wc[j*3 + 2];
    }
    int base = (k >> 5)*512 + (k & 31);
    whd[base + 0*32] = (_Float16)s0;
    whd[base + 1*32] = (_Float16)s1;
    whd[base + 2*32] = (_Float16)s2;
    whd[base + 3*32] = (_Float16)s3;
    for (int o = 4; o < 16; ++o) whd[base + o*32] = (_Float16)0.f;
    if (k < 128){
      int bl = (k >> 5)*512 + (k & 31);
      wlf[bl + 0*32] = (_Float16)Ws[k];
      wlf[bl + 1*32] = (_Float16)Wc[k*3 + 0];
      wlf[bl + 2*32] = (_Float16)Wc[k*3 + 1];
      wlf[bl + 3*32] = (_Float16)Wc[k*3 + 2];
      for (int o = 4; o < 16; ++o) wlf[bl + o*32] = (_Float16)0.f;
    }
    if (k == 0){
      float c0 = bs[0], c1 = bc[0], c2 = bc[1], c3 = bc[2];
      for (int j = 0; j < 128; ++j){
        float bj = b3[j];
        c0 += bj * Ws[j];
        c1 += bj * Wc[j*3 + 0];
        c2 += bj * Wc[j*3 + 1];
        c3 += bj * Wc[j*3 + 2];
      }
      hcon[0] = c0; hcon[1] = c1; hcon[2] = c2; hcon[3] = c3;
      *counter = 0;               // stream order: done before compact_mask runs
    }
  }
}

// ---- compaction + x-packing + zero-write for masked points ----
// px8[slot] = {f16(x0), f16(x1), f16(x2)&~3 | batch, pi_low16}  (8 bytes, one record).
// Batch id (2 bits) stolen from x2's mantissa LSBs: relative error 2^-9, negligible.
// Slot order across blocks is non-deterministic but per-point results depend only on
// that point's row, so final out content is deterministic.
__global__ void compact_mask(const int* __restrict__ mk, const float* __restrict__ x,
                             u16x4* __restrict__ px8,
                             int* __restrict__ counter, float* __restrict__ out){
  __shared__ int woff[16];
  __shared__ int sbase;
  const int tid = threadIdx.x;
  const int i = blockIdx.x*1024 + tid;
  const int lane = tid & 63, w = tid >> 6;
  int m = (mk[i] != 0);
  unsigned long long bal = __ballot(m);
  if (lane == 0) woff[w] = __popcll(bal);
  __syncthreads();
  if (tid == 0){
    int tot = 0;
    #pragma unroll
    for (int k = 0; k < 16; ++k){ int c = woff[k]; woff[k] = tot; tot += c; }
    sbase = atomicAdd(counter, tot);
  }
  __syncthreads();
  if (m){
    int off = __popcll(bal & ((1ull << lane) - 1ull));
    int slot = sbase + woff[w] + off;
    u16x4 r;
    r[0] = f16bits(x[i*3 + 0]);
    r[1] = f16bits(x[i*3 + 1]);
    r[2] = (unsigned short)((f16bits(x[i*3 + 2]) & 0xFFFCu) | (unsigned)(i >> 16));
    r[3] = (unsigned short)(i & 0xFFFF);
    px8[slot] = r;
  } else {
    *(f32x4*)(out + (size_t)i*4) = (f32x4)0.f;
  }
}

// ---- fused main on COMPACTED points: 64 pts/block, 4 waves, 3 barriers ----
// All slot reads are unclamped: reconstructed pi = (px[2]&3)<<16|px[3] is always
// < NPTS, so garbage slots (>= nv, incl. 0xAA poison) give safe addresses; garbage
// rows are row-independent through both GEMMs and never written out.
__global__ __launch_bounds__(256, 4) void field_main(
    const float* __restrict__ rdv,
    const float* __restrict__ lf, const float* __restrict__ b2v,
    const _Float16* __restrict__ base1h, const _Float16* __restrict__ w1h,
    const _Float16* __restrict__ w2t, const _Float16* __restrict__ whd,
    const _Float16* __restrict__ wlf, const float* __restrict__ hcon,
    const float* __restrict__ Wc, const u16x4* __restrict__ px8,
    const int* __restrict__ nvp, float* __restrict__ out)
{
  const int nv = *nvp;
  const int t0 = blockIdx.x * 64;
  if (t0 >= nv) return;

  __shared__ char lds[LDS_BYTES];
  const int tid = threadIdx.x;
  const int wid = tid >> 6, lane = tid & 63;
  const int arow = lane & 15, kgrp = lane >> 4;

  // early prefetch for the epilogue (wave 0 lanes use these)
  int pi_e = 0; float r0 = 0.f, r1 = 0.f, r2 = 0.f;
  if (tid < 64){
    u16x4 px = px8[t0 + tid];
    pi_e = ((px[2] & 3) << 16) | px[3];
    const float* rp = rdv + (pi_e >> 5)*3;
    r0 = rp[0]; r1 = rp[1]; r2 = rp[2];
  }

  const int cw = wid * 64;              // this wave's 64-column slice

  // ---- layer 1: h1 = relu(base1[b] + x @ W1x); x from packed records ----
  {
    const int j0 = (tid & 31) * 8;      // 8 cols per thread
    const int mb = (tid >> 5) * 8;      // 8 rows per thread
    f16x8 w0  = *(const f16x8*)(w1h +   0 + j0);
    f16x8 w1v = *(const f16x8*)(w1h + 256 + j0);
    f16x8 w2v = *(const f16x8*)(w1h + 512 + j0);
    const f16x8 z8 = (f16x8)(_Float16)0;
    #pragma unroll
    for (int m = 0; m < 8; ++m){
      int ii = t0 + mb + m;
      u16x4 px = px8[ii];
      int b = px[2] & 3;
      f16x8 bh = *(const f16x8*)(base1h + b*256 + j0);
      _Float16 X0 = bits16(px[0]);
      _Float16 X1 = bits16(px[1]);
      _Float16 X2 = bits16((unsigned short)(px[2] & 0xFFFCu));
      f16x8 t = bh;
      t += w0  * X0;
      t += w1v * X1;
      t += w2v * X2;
      t = __builtin_elementwise_max(t, z8);
      *(f16x8*)(lds + swz_h(mb + m, j0*2)) = t;
    }
  }
  __syncthreads();                      // (1) h1 complete

  // ---- layer 2: h2 = relu(h1 @ W2 + b2); wave = all 64 rows x its 64 cols ----
  f32x4 acc[16];
  #pragma unroll
  for (int c = 0; c < 4; ++c){
    f32x4 bb = *(const f32x4*)(b2v + cw + c*16 + kgrp*4);
    #pragma unroll
    for (int r = 0; r < 4; ++r) acc[r*4+c] = bb;
  }
  #pragma unroll 2
  for (int s = 0; s < 8; ++s){
    f16x8 af[4], bf[4];
    #pragma unroll
    for (int r = 0; r < 4; ++r)
      af[r] = *(const f16x8*)(lds + swz_h(r*16 + arow, s*64 + kgrp*16));
    #pragma unroll
    for (int c = 0; c < 4; ++c)
      bf[c] = *(const f16x8*)(w2t + s*8192 + (cw + c*16 + arow)*32 + kgrp*8);
    __builtin_amdgcn_s_setprio(1);
    #pragma unroll
    for (int r = 0; r < 4; ++r)
      #pragma unroll
      for (int c = 0; c < 4; ++c)
        acc[r*4+c] = __builtin_amdgcn_mfma_f32_16x16x32_f16(bf[c], af[r], acc[r*4+c], 0, 0, 0);
    __builtin_amdgcn_s_setprio(0);
  }

  // lf gathers issued NOW: HBM latency hides under writeback + head MFMAs.
  f32x4 lfa[4], lfb[4];
  #pragma unroll
  for (int c = 0; c < 4; ++c){
    int ii = t0 + c*16 + arow;
    u16x4 px = px8[ii];
    int pic = ((px[2] & 3) << 16) | px[3];
    const float* lp = lf + (size_t)pic*128 + wid*32 + kgrp*8;
    lfa[c] = *(const f32x4*)lp;
    lfb[c] = *(const f32x4*)(lp + 4);
  }
  __syncthreads();                      // (2) all h1 reads done

  // h2 writeback: own cols of all 64 rows -> ds_write_b64
  #pragma unroll
  for (int r = 0; r < 4; ++r)
    #pragma unroll
    for (int c = 0; c < 4; ++c){
      int row = r*16 + arow;
      int colbyte = (cw + c*16 + kgrp*4) * 2;
      f16x4 v;
      #pragma unroll
      for (int j = 0; j < 4; ++j) v[j] = (_Float16)fmaxf(acc[r*4+c][j], 0.f);
      *(f16x4*)(lds + swz_h(row, colbyte)) = v;
    }

  // ---- self-contained head partials over this wave's K-slices ----
  f32x4 acc4h[4];
  #pragma unroll
  for (int c = 0; c < 4; ++c)
    #pragma unroll
    for (int j = 0; j < 4; ++j)
      acc4h[c][j] = (wid == 0 && kgrp == 0) ? hcon[j] : 0.f;

  // h2 part: K = own 64 cols (reads ONLY locations this wave wrote)
  #pragma unroll
  for (int s = 0; s < 2; ++s){
    f16x8 ah = *(const f16x8*)(whd + (wid*2 + s)*512 + arow*32 + kgrp*8); // A[o][k]
    #pragma unroll
    for (int c = 0; c < 4; ++c){
      f16x8 bh2 = *(const f16x8*)(lds + swz_h(c*16 + arow, (cw + s*32 + kgrp*8)*2));
      acc4h[c] = __builtin_amdgcn_mfma_f32_16x16x32_f16(ah, bh2, acc4h[c], 0, 0, 0);
    }
  }
  // lf part: K-slice [wid*32, wid*32+32)
  {
    f16x8 afl = *(const f16x8*)(wlf + wid*512 + arow*32 + kgrp*8);        // A[o][k]
    #pragma unroll
    for (int c = 0; c < 4; ++c)
      acc4h[c] = __builtin_amdgcn_mfma_f32_16x16x32_f16(afl, cvt8(lfa[c], lfb[c]), acc4h[c], 0, 0, 0);
  }
  // write this wave's partial strip
  if (kgrp == 0){
    #pragma unroll
    for (int c = 0; c < 4; ++c)
      *(f32x4*)(lds + SOFF + wid*1024 + (c*16 + arow)*16) = acc4h[c];
  }
  __syncthreads();                      // (3) all strips complete

  // ---- epilogue: 1 lane per point, sum 4 partials, scatter ----
  if (tid < 64 && t0 + tid < nv){
    f32x4 v = *(const f32x4*)(lds + SOFF + 0*1024 + tid*16);
    #pragma unroll
    for (int w = 1; w < 4; ++w)
      v += *(const f32x4*)(lds + SOFF + w*1024 + tid*16);
    float ps = v[0] - 1.0f;
    float shape = (ps > 20.f) ? ps : log1pf(expf(ps));
    float c0 = v[1] + r0*Wc[128*3+0] + r1*Wc[129*3+0] + r2*Wc[130*3+0];
    float c1 = v[2] + r0*Wc[128*3+1] + r1*Wc[129*3+1] + r2*Wc[130*3+1];
    float c2 = v[3] + r0*Wc[128*3+2] + r1*Wc[129*3+2] + r2*Wc[130*3+2];
    f32x4 o;
    o[0] = shape;
    o[1] = 1.f/(1.f + expf(-c0));
    o[2] = 1.f/(1.f + expf(-c1));
    o[3] = 1.f/(1.f + expf(-c2));
    *(f32x4*)(out + (size_t)pi_e*4) = o;
  }
}

extern "C" void kernel_launch(void* const* d_in, const int* in_sizes, int n_in,
                              void* d_out, int out_size, void* d_ws, size_t ws_size,
                              hipStream_t stream){
  const float* x   = (const float*)d_in[0];
  const float* rd  = (const float*)d_in[1];
  const int*   mk  = (const int*)d_in[2];
  const float* gf  = (const float*)d_in[3];
  const float* off = (const float*)d_in[4];
  const float* lf  = (const float*)d_in[5];
  const float* W1  = (const float*)d_in[6];
  const float* b1  = (const float*)d_in[7];
  const float* W2  = (const float*)d_in[8];
  const float* b2  = (const float*)d_in[9];
  const float* W3  = (const float*)d_in[10];
  const float* b3  = (const float*)d_in[11];
  const float* Ws  = (const float*)d_in[12];
  const float* bs  = (const float*)d_in[13];
  const float* Wc  = (const float*)d_in[14];
  const float* bc  = (const float*)d_in[15];

  char* ws = (char*)d_ws;
  _Float16* base1h    = (_Float16*)(ws + 0);         // 2048 B
  _Float16* w1h       = (_Float16*)(ws + 2048);      // 1536 B
  _Float16* w2t       = (_Float16*)(ws + 4096);      // 131072 B
  _Float16* whd       = (_Float16*)(ws + 135168);    // 8192 B
  _Float16* wlf       = (_Float16*)(ws + 143360);    // 4096 B
  float*    hcon      = (float*)   (ws + 147456);    // 16 B
  int*      counter   = (int*)     (ws + 147472);    // 4 B
  u16x4*    px8       = (u16x4*)   (ws + 147712);    // 2 MB

  prep_all<<<70, 256, 0, stream>>>(gf, off, W1, b1, W2, W3, b3, Ws, bs, Wc, bc,
                                   w2t, w1h, base1h, whd, wlf, hcon, counter);
  compact_mask<<<NPTS/1024, 1024, 0, stream>>>(mk, x, px8, counter, (float*)d_out);
  field_main<<<NPTS/64, 256, 0, stream>>>(rd, lf, b2,
                                          base1h, w1h, w2t, whd, wlf, hcon, Wc,
                                          px8, counter, (float*)d_out);
}

// Round 19
// 58.470 us; speedup vs baseline: 1.4487x; 1.0135x over previous
//
#include <hip/hip_runtime.h>

typedef __attribute__((ext_vector_type(8))) _Float16 f16x8;
typedef __attribute__((ext_vector_type(4))) _Float16 f16x4;
typedef __attribute__((ext_vector_type(4))) float f32x4;
typedef __attribute__((ext_vector_type(4))) unsigned short u16x4;

#define SOFF 32768
#define LDS_BYTES (32768 + 4096)   // h1/h2 f16 [64][256] aliased; strips (and pic stash)
#define NPTS 262144

// h1/h2: f16 [64 rows][256 cols], row stride 512B, XOR-swizzled
__device__ inline unsigned swz_h(unsigned row, unsigned colbyte){
  return row*512u + (colbyte ^ ((row & 7u) << 4));
}

__device__ inline f16x8 cvt8(f32x4 a, f32x4 b){
  f16x8 r;
  #pragma unroll
  for (int i = 0; i < 4; ++i){ r[i] = (_Float16)a[i]; r[4+i] = (_Float16)b[i]; }
  return r;
}

__device__ inline unsigned short f16bits(float f){
  _Float16 h = (_Float16)f;
  return *(unsigned short*)&h;
}
__device__ inline _Float16 bits16(unsigned short u){
  return *(_Float16*)&u;
}

// ---- merged prep (70 blocks): 0-63 W2 tile; 64 w1h; 65-68 base1; 69 head fold ----
__global__ void prep_all(const float* __restrict__ gf, const float* __restrict__ off,
                         const float* __restrict__ W1, const float* __restrict__ b1,
                         const float* __restrict__ W2,
                         const float* __restrict__ W3, const float* __restrict__ b3,
                         const float* __restrict__ Ws, const float* __restrict__ bs,
                         const float* __restrict__ Wc, const float* __restrict__ bc,
                         _Float16* __restrict__ w2t, _Float16* __restrict__ w1h,
                         _Float16* __restrict__ base1h,
                         _Float16* __restrict__ whd, _Float16* __restrict__ wlf,
                         float* __restrict__ hcon, int* __restrict__ counter){
  const int blk = blockIdx.x, tid = threadIdx.x;
  if (blk < 64){
    #pragma unroll
    for (int k = 0; k < 4; ++k){
      int e = blk*1024 + k*256 + tid;
      int s = e >> 13, r = e & 8191, n = r >> 5, kk = r & 31;
      w2t[e] = (_Float16)W2[(s*32 + kk)*256 + n];
    }
  } else if (blk == 64){
    #pragma unroll
    for (int k = 0; k < 3; ++k){
      int e = k*256 + tid;
      int d = e >> 8, j = e & 255;
      w1h[e] = (_Float16)W1[(256 + d)*256 + j];
    }
  } else if (blk < 69){
    int b = blk - 65, j = tid;
    float acc = b1[j];
    for (int k = 0; k < 256; ++k) acc += gf[b*256 + k] * W1[k*256 + j];
    for (int d = 0; d < 3; ++d)  acc -= off[b*3 + d] * W1[(256 + d)*256 + j];
    base1h[b*256 + j] = (_Float16)acc;
  } else {
    int k = tid;      // 0..255
    float s0 = 0.f, s1 = 0.f, s2 = 0.f, s3 = 0.f;
    for (int j = 0; j < 128; ++j){
      float w3 = W3[k*128 + j];
      s0 += w3 * Ws[j];
      s1 += w3 * Wc[j*3 + 0];
      s2 += w3 * Wc[j*3 + 1];
      s3 += w3 * Wc[j*3 + 2];
    }
    int base = (k >> 5)*512 + (k & 31);
    whd[base + 0*32] = (_Float16)s0;
    whd[base + 1*32] = (_Float16)s1;
    whd[base + 2*32] = (_Float16)s2;
    whd[base + 3*32] = (_Float16)s3;
    for (int o = 4; o < 16; ++o) whd[base + o*32] = (_Float16)0.f;
    if (k < 128){
      int bl = (k >> 5)*512 + (k & 31);
      wlf[bl + 0*32] = (_Float16)Ws[k];
      wlf[bl + 1*32] = (_Float16)Wc[k*3 + 0];
      wlf[bl + 2*32] = (_Float16)Wc[k*3 + 1];
      wlf[bl + 3*32] = (_Float16)Wc[k*3 + 2];
      for (int o = 4; o < 16; ++o) wlf[bl + o*32] = (_Float16)0.f;
    }
    if (k == 0){
      float c0 = bs[0], c1 = bc[0], c2 = bc[1], c3 = bc[2];
      for (int j = 0; j < 128; ++j){
        float bj = b3[j];
        c0 += bj * Ws[j];
        c1 += bj * Wc[j*3 + 0];
        c2 += bj * Wc[j*3 + 1];
        c3 += bj * Wc[j*3 + 2];
      }
      hcon[0] = c0; hcon[1] = c1; hcon[2] = c2; hcon[3] = c3;
      *counter = 0;               // stream order: done before compact_mask runs
    }
  }
}

// ---- compaction + x-packing + zero-write for masked points ----
// px8[slot] = {f16(x0), f16(x1), f16(x2)&~3 | batch, pi_low16}  (8 bytes, one record).
// Batch id (2 bits) stolen from x2's mantissa LSBs: relative error 2^-9, negligible.
// Slot order across blocks is non-deterministic but per-point results depend only on
// that point's row, so final out content is deterministic.
__global__ void compact_mask(const int* __restrict__ mk, const float* __restrict__ x,
                             u16x4* __restrict__ px8,
                             int* __restrict__ counter, float* __restrict__ out){
  __shared__ int woff[16];
  __shared__ int sbase;
  const int tid = threadIdx.x;
  const int i = blockIdx.x*1024 + tid;
  const int lane = tid & 63, w = tid >> 6;
  int m = (mk[i] != 0);
  unsigned long long bal = __ballot(m);
  if (lane == 0) woff[w] = __popcll(bal);
  __syncthreads();
  if (tid == 0){
    int tot = 0;
    #pragma unroll
    for (int k = 0; k < 16; ++k){ int c = woff[k]; woff[k] = tot; tot += c; }
    sbase = atomicAdd(counter, tot);
  }
  __syncthreads();
  if (m){
    int off = __popcll(bal & ((1ull << lane) - 1ull));
    int slot = sbase + woff[w] + off;
    u16x4 r;
    r[0] = f16bits(x[i*3 + 0]);
    r[1] = f16bits(x[i*3 + 1]);
    r[2] = (unsigned short)((f16bits(x[i*3 + 2]) & 0xFFFCu) | (unsigned)(i >> 16));
    r[3] = (unsigned short)(i & 0xFFFF);
    px8[slot] = r;
  } else {
    *(f32x4*)(out + (size_t)i*4) = (f32x4)0.f;
  }
}

// ---- fused main on COMPACTED points: 64 pts/block, 4 waves, 3 barriers ----
// All slot reads are unclamped: reconstructed pi = (px[2]&3)<<16|px[3] is always
// < NPTS, so garbage slots (>= nv, incl. 0xAA poison) give safe addresses; garbage
// rows are row-independent through both GEMMs and never written out.
__global__ __launch_bounds__(256, 4) void field_main(
    const float* __restrict__ rdv,
    const float* __restrict__ lf, const float* __restrict__ b2v,
    const _Float16* __restrict__ base1h, const _Float16* __restrict__ w1h,
    const _Float16* __restrict__ w2t, const _Float16* __restrict__ whd,
    const _Float16* __restrict__ wlf, const float* __restrict__ hcon,
    const float* __restrict__ Wc, const u16x4* __restrict__ px8,
    const int* __restrict__ nvp, float* __restrict__ out)
{
  const int nv = *nvp;
  const int t0 = blockIdx.x * 64;
  if (t0 >= nv) return;

  __shared__ char lds[LDS_BYTES];
  const int tid = threadIdx.x;
  const int wid = tid >> 6, lane = tid & 63;
  const int arow = lane & 15, kgrp = lane >> 4;

  // early prefetch for the epilogue + pic stash for the lf gather.
  // Stash lifetime: written pre-barrier(1), read pre-barrier(2); strip writes
  // (same region) happen post-barrier(2) -> no race.
  int pi_e = 0; float r0 = 0.f, r1 = 0.f, r2 = 0.f;
  if (tid < 64){
    u16x4 px = px8[t0 + tid];
    pi_e = ((px[2] & 3) << 16) | px[3];
    *(int*)(lds + SOFF + tid*4) = pi_e;
    const float* rp = rdv + (pi_e >> 5)*3;
    r0 = rp[0]; r1 = rp[1]; r2 = rp[2];
  }

  const int cw = wid * 64;              // this wave's 64-column slice

  // ---- layer 1: h1 = relu(base1[b] + x @ W1x); x from packed records ----
  {
    const int j0 = (tid & 31) * 8;      // 8 cols per thread
    const int mb = (tid >> 5) * 8;      // 8 rows per thread
    f16x8 w0  = *(const f16x8*)(w1h +   0 + j0);
    f16x8 w1v = *(const f16x8*)(w1h + 256 + j0);
    f16x8 w2v = *(const f16x8*)(w1h + 512 + j0);
    const f16x8 z8 = (f16x8)(_Float16)0;
    #pragma unroll
    for (int m = 0; m < 8; ++m){
      int ii = t0 + mb + m;
      u16x4 px = px8[ii];
      int b = px[2] & 3;
      f16x8 bh = *(const f16x8*)(base1h + b*256 + j0);
      _Float16 X0 = bits16(px[0]);
      _Float16 X1 = bits16(px[1]);
      _Float16 X2 = bits16((unsigned short)(px[2] & 0xFFFCu));
      f16x8 t = bh;
      t += w0  * X0;
      t += w1v * X1;
      t += w2v * X2;
      t = __builtin_elementwise_max(t, z8);
      *(f16x8*)(lds + swz_h(mb + m, j0*2)) = t;
    }
  }
  __syncthreads();                      // (1) h1 + pic stash complete

  // ---- layer 2: h2 = relu(h1 @ W2 + b2); wave = all 64 rows x its 64 cols ----
  f32x4 acc[16];
  #pragma unroll
  for (int c = 0; c < 4; ++c){
    f32x4 bb = *(const f32x4*)(b2v + cw + c*16 + kgrp*4);
    #pragma unroll
    for (int r = 0; r < 4; ++r) acc[r*4+c] = bb;
  }
  #pragma unroll 2
  for (int s = 0; s < 8; ++s){
    f16x8 af[4], bf[4];
    #pragma unroll
    for (int r = 0; r < 4; ++r)
      af[r] = *(const f16x8*)(lds + swz_h(r*16 + arow, s*64 + kgrp*16));
    #pragma unroll
    for (int c = 0; c < 4; ++c)
      bf[c] = *(const f16x8*)(w2t + s*8192 + (cw + c*16 + arow)*32 + kgrp*8);
    __builtin_amdgcn_s_setprio(1);
    #pragma unroll
    for (int r = 0; r < 4; ++r)
      #pragma unroll
      for (int c = 0; c < 4; ++c)
        acc[r*4+c] = __builtin_amdgcn_mfma_f32_16x16x32_f16(bf[c], af[r], acc[r*4+c], 0, 0, 0);
    __builtin_amdgcn_s_setprio(0);
  }

  // lf gathers issued NOW: pic from LDS stash (short chain), HBM latency hides
  // under writeback + head MFMAs.
  f32x4 lfa[4], lfb[4];
  #pragma unroll
  for (int c = 0; c < 4; ++c){
    int pic = *(const int*)(lds + SOFF + (c*16 + arow)*4);
    const float* lp = lf + (size_t)pic*128 + wid*32 + kgrp*8;
    lfa[c] = *(const f32x4*)lp;
    lfb[c] = *(const f32x4*)(lp + 4);
  }
  __syncthreads();                      // (2) all h1 reads + stash reads done

  // h2 writeback: own cols of all 64 rows -> ds_write_b64
  #pragma unroll
  for (int r = 0; r < 4; ++r)
    #pragma unroll
    for (int c = 0; c < 4; ++c){
      int row = r*16 + arow;
      int colbyte = (cw + c*16 + kgrp*4) * 2;
      f16x4 v;
      #pragma unroll
      for (int j = 0; j < 4; ++j) v[j] = (_Float16)fmaxf(acc[r*4+c][j], 0.f);
      *(f16x4*)(lds + swz_h(row, colbyte)) = v;
    }

  // ---- self-contained head partials over this wave's K-slices ----
  f32x4 acc4h[4];
  #pragma unroll
  for (int c = 0; c < 4; ++c)
    #pragma unroll
    for (int j = 0; j < 4; ++j)
      acc4h[c][j] = (wid == 0 && kgrp == 0) ? hcon[j] : 0.f;

  // h2 part: K = own 64 cols (reads ONLY locations this wave wrote)
  #pragma unroll
  for (int s = 0; s < 2; ++s){
    f16x8 ah = *(const f16x8*)(whd + (wid*2 + s)*512 + arow*32 + kgrp*8); // A[o][k]
    #pragma unroll
    for (int c = 0; c < 4; ++c){
      f16x8 bh2 = *(const f16x8*)(lds + swz_h(c*16 + arow, (cw + s*32 + kgrp*8)*2));
      acc4h[c] = __builtin_amdgcn_mfma_f32_16x16x32_f16(ah, bh2, acc4h[c], 0, 0, 0);
    }
  }
  // lf part: K-slice [wid*32, wid*32+32)
  {
    f16x8 afl = *(const f16x8*)(wlf + wid*512 + arow*32 + kgrp*8);        // A[o][k]
    #pragma unroll
    for (int c = 0; c < 4; ++c)
      acc4h[c] = __builtin_amdgcn_mfma_f32_16x16x32_f16(afl, cvt8(lfa[c], lfb[c]), acc4h[c], 0, 0, 0);
  }
  // write this wave's partial strip
  if (kgrp == 0){
    #pragma unroll
    for (int c = 0; c < 4; ++c)
      *(f32x4*)(lds + SOFF + wid*1024 + (c*16 + arow)*16) = acc4h[c];
  }
  __syncthreads();                      // (3) all strips complete

  // ---- epilogue: 1 lane per point, sum 4 partials, scatter ----
  if (tid < 64 && t0 + tid < nv){
    f32x4 v = *(const f32x4*)(lds + SOFF + 0*1024 + tid*16);
    #pragma unroll
    for (int w = 1; w < 4; ++w)
      v += *(const f32x4*)(lds + SOFF + w*1024 + tid*16);
    float ps = v[0] - 1.0f;
    float shape = (ps > 20.f) ? ps : log1pf(expf(ps));
    float c0 = v[1] + r0*Wc[128*3+0] + r1*Wc[129*3+0] + r2*Wc[130*3+0];
    float c1 = v[2] + r0*Wc[128*3+1] + r1*Wc[129*3+1] + r2*Wc[130*3+1];
    float c2 = v[3] + r0*Wc[128*3+2] + r1*Wc[129*3+2] + r2*Wc[130*3+2];
    f32x4 o;
    o[0] = shape;
    o[1] = 1.f/(1.f + expf(-c0));
    o[2] = 1.f/(1.f + expf(-c1));
    o[3] = 1.f/(1.f + expf(-c2));
    *(f32x4*)(out + (size_t)pi_e*4) = o;
  }
}

extern "C" void kernel_launch(void* const* d_in, const int* in_sizes, int n_in,
                              void* d_out, int out_size, void* d_ws, size_t ws_size,
                              hipStream_t stream){
  const float* x   = (const float*)d_in[0];
  const float* rd  = (const float*)d_in[1];
  const int*   mk  = (const int*)d_in[2];
  const float* gf  = (const float*)d_in[3];
  const float* off = (const float*)d_in[4];
  const float* lf  = (const float*)d_in[5];
  const float* W1  = (const float*)d_in[6];
  const float* b1  = (const float*)d_in[7];
  const float* W2  = (const float*)d_in[8];
  const float* b2  = (const float*)d_in[9];
  const float* W3  = (const float*)d_in[10];
  const float* b3  = (const float*)d_in[11];
  const float* Ws  = (const float*)d_in[12];
  const float* bs  = (const float*)d_in[13];
  const float* Wc  = (const float*)d_in[14];
  const float* bc  = (const float*)d_in[15];

  char* ws = (char*)d_ws;
  _Float16* base1h    = (_Float16*)(ws + 0);         // 2048 B
  _Float16* w1h       = (_Float16*)(ws + 2048);      // 1536 B
  _Float16* w2t       = (_Float16*)(ws + 4096);      // 131072 B
  _Float16* whd       = (_Float16*)(ws + 135168);    // 8192 B
  _Float16* wlf       = (_Float16*)(ws + 143360);    // 4096 B
  float*    hcon      = (float*)   (ws + 147456);    // 16 B
  int*      counter   = (int*)     (ws + 147472);    // 4 B
  u16x4*    px8       = (u16x4*)   (ws + 147712);    // 2 MB

  prep_all<<<70, 256, 0, stream>>>(gf, off, W1, b1, W2, W3, b3, Ws, bs, Wc, bc,
                                   w2t, w1h, base1h, whd, wlf, hcon, counter);
  compact_mask<<<NPTS/1024, 1024, 0, stream>>>(mk, x, px8, counter, (float*)d_out);
  field_main<<<NPTS/64, 256, 0, stream>>>(rd, lf, b2,
                                          base1h, w1h, w2t, whd, wlf, hcon, Wc,
                                          px8, counter, (float*)d_out);
}